// Round 1
// baseline (181.751 us; speedup 1.0000x reference)
//
#include <hip/hip_runtime.h>

#define NQ 12
#define DIM 4096        // 2^12 amplitudes
#define THREADS 256

// ---------- complex helpers (float2 = {re, im}) ----------
__device__ inline float2 cmul(float2 a, float2 b) {
    return make_float2(a.x * b.x - a.y * b.y, a.x * b.y + a.y * b.x);
}
__device__ inline float2 cadd(float2 a, float2 b) { return make_float2(a.x + b.x, a.y + b.y); }
__device__ inline float2 csub(float2 a, float2 b) { return make_float2(a.x - b.x, a.y - b.y); }
__device__ inline float2 conjc(float2 a) { return make_float2(a.x, -a.y); }

// 2x2 complex matrices, row-major m[0]=m00 m[1]=m01 m[2]=m10 m[3]=m11
__device__ inline void mat_rx(float c, float s, float2 m[4]) {
    m[0] = make_float2(c, 0.f);  m[1] = make_float2(0.f, -s);
    m[2] = make_float2(0.f, -s); m[3] = make_float2(c, 0.f);
}
__device__ inline void mat_ry(float c, float s, float2 m[4]) {
    m[0] = make_float2(c, 0.f);  m[1] = make_float2(-s, 0.f);
    m[2] = make_float2(s, 0.f);  m[3] = make_float2(c, 0.f);
}
__device__ inline void mmul(const float2 A[4], const float2 B[4], float2 C[4]) {
    C[0] = cadd(cmul(A[0], B[0]), cmul(A[1], B[2]));
    C[1] = cadd(cmul(A[0], B[1]), cmul(A[1], B[3]));
    C[2] = cadd(cmul(A[2], B[0]), cmul(A[3], B[2]));
    C[3] = cadd(cmul(A[2], B[1]), cmul(A[3], B[3]));
}

// One block per batch element. State (4096 complex64 = 32 KB) lives in LDS.
// Wire w <-> flat-index bit (11 - w)  (axis 1 of the reference state = wire 0 = MSB).
__global__ __launch_bounds__(THREADS) void qcnn_kernel(
    const float* __restrict__ x,      // [B,1,14,14]
    const float* __restrict__ cw,     // [1,1,4,4]
    const float* __restrict__ cb,     // [1]
    const float* __restrict__ th,     // [3]
    float* __restrict__ out)          // [B,2]
{
    __shared__ float2 st[DIM];
    __shared__ float  xs[196];
    __shared__ float  f[36];
    __shared__ float2 uq[NQ][2];   // encoder1 state per qubit: U1|0>
    __shared__ float2 Vq[NQ][4];   // encoder2 fused 2x2 per qubit
    __shared__ float  red[4][6];   // per-wave reduction partials

    const int tid = threadIdx.x;
    const int b   = blockIdx.x;

    // ---- load input tile ----
    if (tid < 196) xs[tid] = x[(size_t)b * 196 + tid];
    __syncthreads();

    // ---- conv 4x4 stride 2 valid -> 36 features ----
    if (tid < 36) {
        int oy = tid / 6, ox = tid % 6;
        float acc = cb[0];
#pragma unroll
        for (int ky = 0; ky < 4; ++ky)
#pragma unroll
            for (int kx = 0; kx < 4; ++kx)
                acc += xs[(2 * oy + ky) * 14 + (2 * ox + kx)] * cw[ky * 4 + kx];
        f[tid] = acc;
    }
    __syncthreads();

    // ---- per-qubit fused gate matrices ----
    if (tid < NQ) {
        float a0 = f[tid * 3 + 0], a1 = f[tid * 3 + 1], a2 = f[tid * 3 + 2];
        float c0, s0, c1, s1, c2, s2;
        sincosf(0.5f * a0, &s0, &c0);
        sincosf(0.5f * a1, &s1, &c1);
        sincosf(0.5f * a2, &s2, &c2);

        float2 mA[4], mB[4], mC[4], t0m[4], U[4];
        // encoder1: U1 = RX(a2) * RY(a1) * RX(a0); u = first column
        mat_rx(c0, s0, mA);
        mat_ry(c1, s1, mB);
        mat_rx(c2, s2, mC);
        mmul(mB, mA, t0m);
        mmul(mC, t0m, U);
        uq[tid][0] = U[0];
        uq[tid][1] = U[2];
        // encoder2: V = RY(a2) * RX(a1) * RY(a0)
        mat_ry(c0, s0, mA);
        mat_rx(c1, s1, mB);
        mat_ry(c2, s2, mC);
        mmul(mB, mA, t0m);
        mmul(mC, t0m, U);
        Vq[tid][0] = U[0]; Vq[tid][1] = U[1];
        Vq[tid][2] = U[2]; Vq[tid][3] = U[3];
    }
    __syncthreads();

    // ---- build product state: amp[j] = prod_q uq[q][bit_{11-q}(j)] ----
    // j = tid*16 + l : tid bits 7..0 -> qubits 0..7, l bits 3..0 -> qubits 8..11
    {
        float2 pre = make_float2(1.f, 0.f);
#pragma unroll
        for (int q = 0; q < 8; ++q)
            pre = cmul(pre, uq[q][(tid >> (7 - q)) & 1]);
#pragma unroll
        for (int l = 0; l < 16; ++l) {
            float2 amp = pre;
#pragma unroll
            for (int q = 8; q < 12; ++q)
                amp = cmul(amp, uq[q][(l >> (11 - q)) & 1]);
            st[tid * 16 + l] = amp;
        }
    }
    __syncthreads();

    // ---- iSWAP ascending: wires (11-i, 10-i) -> bit shifts (i, i+1) ----
    for (int g = 0; g < 11; ++g) {
        int s = g;
        for (int p = tid; p < DIM / 4; p += THREADS) {
            int base = ((p >> s) << (s + 2)) | (p & ((1 << s) - 1));
            int ja = base | (1 << s);
            int jb = base | (2 << s);
            float2 a = st[ja], c = st[jb];
            st[ja] = make_float2(-c.y, c.x);   // i * c
            st[jb] = make_float2(-a.y, a.x);   // i * a
        }
        __syncthreads();
    }

    // ---- encoder2: fused 1q gate per qubit ----
    for (int q = 0; q < NQ; ++q) {
        int s = 11 - q;
        float2 v00 = Vq[q][0], v01 = Vq[q][1], v10 = Vq[q][2], v11 = Vq[q][3];
        for (int p = tid; p < DIM / 2; p += THREADS) {
            int j0 = ((p >> s) << (s + 1)) | (p & ((1 << s) - 1));
            int j1 = j0 | (1 << s);
            float2 a0 = st[j0], a1 = st[j1];
            st[j0] = cadd(cmul(v00, a0), cmul(v01, a1));
            st[j1] = cadd(cmul(v10, a0), cmul(v11, a1));
        }
        __syncthreads();
    }

    // ---- iSWAP descending: wires (i+1, i) -> bit shifts (10-i, 11-i) ----
    for (int g = 0; g < 11; ++g) {
        int s = 10 - g;
        for (int p = tid; p < DIM / 4; p += THREADS) {
            int base = ((p >> s) << (s + 2)) | (p & ((1 << s) - 1));
            int ja = base | (1 << s);
            int jb = base | (2 << s);
            float2 a = st[ja], c = st[jb];
            st[ja] = make_float2(-c.y, c.x);
            st[jb] = make_float2(-a.y, a.x);
        }
        __syncthreads();
    }

    // ---- expectations: O = (RY(t1) RX(t0))^dag Z (RY(t1) RX(t0)) on wires 0,1
    //      (RZ commutes with Z; final gates never applied to the state) ----
    float d0 = 0.f, c0r = 0.f, c0i = 0.f;
    float d1 = 0.f, c1r = 0.f, c1i = 0.f;
    for (int p = tid; p < DIM / 2; p += THREADS) {
        {   // wire 0: bit 11
            float2 a0 = st[p];
            float2 a1 = st[p + 2048];
            d0  += (a0.x * a0.x + a0.y * a0.y) - (a1.x * a1.x + a1.y * a1.y);
            c0r += a0.x * a1.x + a0.y * a1.y;       // Re(conj(a0)*a1)
            c0i += a0.x * a1.y - a0.y * a1.x;       // Im(conj(a0)*a1)
        }
        {   // wire 1: bit 10
            int j0 = ((p >> 10) << 11) | (p & 1023);
            int j1 = j0 | 1024;
            float2 a0 = st[j0], a1 = st[j1];
            d1  += (a0.x * a0.x + a0.y * a0.y) - (a1.x * a1.x + a1.y * a1.y);
            c1r += a0.x * a1.x + a0.y * a1.y;
            c1i += a0.x * a1.y - a0.y * a1.x;
        }
    }
    // wave (64-lane) reduction
#pragma unroll
    for (int off = 32; off; off >>= 1) {
        d0  += __shfl_down(d0, off);
        c0r += __shfl_down(c0r, off);
        c0i += __shfl_down(c0i, off);
        d1  += __shfl_down(d1, off);
        c1r += __shfl_down(c1r, off);
        c1i += __shfl_down(c1i, off);
    }
    if ((tid & 63) == 0) {
        int w = tid >> 6;
        red[w][0] = d0;  red[w][1] = c0r; red[w][2] = c0i;
        red[w][3] = d1;  red[w][4] = c1r; red[w][5] = c1i;
    }
    __syncthreads();
    if (tid == 0) {
        float D0 = 0, C0r = 0, C0i = 0, D1 = 0, C1r = 0, C1i = 0;
#pragma unroll
        for (int w = 0; w < 4; ++w) {
            D0 += red[w][0]; C0r += red[w][1]; C0i += red[w][2];
            D1 += red[w][3]; C1r += red[w][4]; C1i += red[w][5];
        }
        float ct0, st0, ct1, st1;
        sincosf(0.5f * th[0], &st0, &ct0);
        sincosf(0.5f * th[1], &st1, &ct1);
        float2 Rx[4], Ry[4], M[4];
        mat_rx(ct0, st0, Rx);
        mat_ry(ct1, st1, Ry);
        mmul(Ry, Rx, M);
        // O = M^dag Z M ; o11 = -o00
        float  o00 = (M[0].x * M[0].x + M[0].y * M[0].y)
                   - (M[2].x * M[2].x + M[2].y * M[2].y);
        float2 o01 = csub(cmul(conjc(M[0]), M[1]), cmul(conjc(M[2]), M[3]));
        out[b * 2 + 0] = o00 * D0 + 2.f * (o01.x * C0r - o01.y * C0i);
        out[b * 2 + 1] = o00 * D1 + 2.f * (o01.x * C1r - o01.y * C1i);
    }
}

extern "C" void kernel_launch(void* const* d_in, const int* in_sizes, int n_in,
                              void* d_out, int out_size, void* d_ws, size_t ws_size,
                              hipStream_t stream) {
    const float* x  = (const float*)d_in[0];
    const float* cw = (const float*)d_in[1];
    const float* cb = (const float*)d_in[2];
    const float* th = (const float*)d_in[3];
    float* out = (float*)d_out;
    int B = in_sizes[0] / 196;   // 4096
    qcnn_kernel<<<B, THREADS, 0, stream>>>(x, cw, cb, th, out);
}

// Round 2
// 19.174 us; speedup vs baseline: 9.4791x; 9.4791x over previous
//
#include <hip/hip_runtime.h>

#define NQ 12

// ---------- complex helpers (float2 = {re, im}) ----------
__device__ __forceinline__ float2 cmul(float2 a, float2 b) {
    return make_float2(a.x * b.x - a.y * b.y, a.x * b.y + a.y * b.x);
}
__device__ __forceinline__ float2 cadd(float2 a, float2 b) { return make_float2(a.x + b.x, a.y + b.y); }
__device__ __forceinline__ float2 csub(float2 a, float2 b) { return make_float2(a.x - b.x, a.y - b.y); }
__device__ __forceinline__ float2 conjc(float2 a) { return make_float2(a.x, -a.y); }
__device__ __forceinline__ float2 cmuli(float2 a) { return make_float2(-a.y, a.x); }  // i*a
__device__ __forceinline__ float2 cdot(float2 a, float2 b) {                          // conj(a)*b
    return make_float2(a.x * b.x + a.y * b.y, a.x * b.y - a.y * b.x);
}
__device__ __forceinline__ float2 cscale(float s, float2 a) { return make_float2(s * a.x, s * a.y); }

// 2x2 complex matrices, row-major m[0]=m00 m[1]=m01 m[2]=m10 m[3]=m11
__device__ __forceinline__ void mat_rx(float c, float s, float2 m[4]) {
    m[0] = make_float2(c, 0.f);  m[1] = make_float2(0.f, -s);
    m[2] = make_float2(0.f, -s); m[3] = make_float2(c, 0.f);
}
__device__ __forceinline__ void mat_ry(float c, float s, float2 m[4]) {
    m[0] = make_float2(c, 0.f);  m[1] = make_float2(-s, 0.f);
    m[2] = make_float2(s, 0.f);  m[3] = make_float2(c, 0.f);
}
__device__ __forceinline__ void mmul(const float2 A[4], const float2 B[4], float2 C[4]) {
    C[0] = cadd(cmul(A[0], B[0]), cmul(A[1], B[2]));
    C[1] = cadd(cmul(A[0], B[1]), cmul(A[1], B[3]));
    C[2] = cadd(cmul(A[2], B[0]), cmul(A[3], B[2]));
    C[3] = cadd(cmul(A[2], B[1]), cmul(A[3], B[3]));
}

// Closed-form evaluation. Flat-index bit t <-> wire (11-t).
//
// Encoder1 gives product state  st0[j] = prod_t a_t[j_t],  a_t = u_{11-t} = (RX RY RX)|0>.
// Ascending iSWAP chain (monomial): bubbles bit0 up:  st1[j] = a_0[j11] *
//   prod_{t=0..10} ( a_{t+1}[j_t] * i^{[j_t != j11]} ) — rank-2 sum of product
//   states over v = j11.  Branch v factors: pos 11: a_0[v] e_v; pos t<=10:
//   g^v_t[b] = a_{t+1}[b] i^{[b!=v]}.
// Encoder2 (1q gates V_q on pos 11-q) keeps product structure:
//   h^v_11[b] = a_0[v] V_0[b,v];  h^v_t = V_{11-t} g^v_t.
// Descending chain bubbles bit11 down:  st3[j] = sum_v h^v_11[j0] *
//   prod_{r=1..11} ( h^v_{r-1}[j_r] * i^{[j_r != j0]} ).
// The i^{[.!=j0]} phases cancel in plain inner products; they survive only as
// O^w = D_w^dag O D_w (D_w = diag(i^[0!=w], i^[1!=w])) at the observable slot.
// <O_t> = sum_w sum_{v,v'} conj(h^v_11[w]) h^{v'}_11[w]
//          * (sum_{bg} conj(h^v_{t-1}[b]) O^w[b,g] h^{v'}_{t-1}[g])
//          * prod_{m in 0..10, m != t-1} <h^v_m, h^{v'}_m>.
// Observables: wire0 -> bit 11 (factor m=10), wire1 -> bit 10 (factor m=9);
// O = (RY RX)^dag Z (RY RX) (RZ commutes with Z).
__global__ __launch_bounds__(64) void qcnn_closed(
    const float* __restrict__ x,      // [B,1,14,14]
    const float* __restrict__ cw,     // [1,1,4,4]
    const float* __restrict__ cb,     // [1]
    const float* __restrict__ th,     // [3]
    float* __restrict__ out,          // [B,2]
    int B)
{
    const int b = blockIdx.x * 64 + threadIdx.x;
    if (b >= B) return;

    // ---- conv 4x4 stride 2 valid -> 36 feature angles ----
    float wgt[16];
#pragma unroll
    for (int k = 0; k < 16; ++k) wgt[k] = cw[k];
    const float bias = cb[0];
    const float* xb = x + (size_t)b * 196;

    float f[36];
#pragma unroll
    for (int oy = 0; oy < 6; ++oy) {
#pragma unroll
        for (int ox = 0; ox < 6; ++ox) {
            float acc = bias;
#pragma unroll
            for (int ky = 0; ky < 4; ++ky) {
#pragma unroll
                for (int kx = 0; kx < 4; ++kx)
                    acc += xb[(2 * oy + ky) * 14 + (2 * ox + kx)] * wgt[ky * 4 + kx];
            }
            f[oy * 6 + ox] = acc;
        }
    }

    // ---- per-qubit encoder1 vectors u_q = (RX(a2) RY(a1) RX(a0)) |0> ----
    float2 u[NQ][2];
#pragma unroll
    for (int q = 0; q < NQ; ++q) {
        float c0, s0, c1, s1, c2, s2;
        sincosf(0.5f * f[3 * q + 0], &s0, &c0);
        sincosf(0.5f * f[3 * q + 1], &s1, &c1);
        sincosf(0.5f * f[3 * q + 2], &s2, &c2);
        float2 A[4], Bm[4], Cm[4], T[4], U[4];
        mat_rx(c0, s0, A); mat_ry(c1, s1, Bm); mat_rx(c2, s2, Cm);
        mmul(Bm, A, T); mmul(Cm, T, U);
        u[q][0] = U[0]; u[q][1] = U[2];
    }

    // ---- branch factor vectors h[v][pos][beta] ----
    float2 h[2][NQ][2];
#pragma unroll
    for (int q = 0; q < NQ; ++q) {
        float c0, s0, c1, s1, c2, s2;
        sincosf(0.5f * f[3 * q + 0], &s0, &c0);
        sincosf(0.5f * f[3 * q + 1], &s1, &c1);
        sincosf(0.5f * f[3 * q + 2], &s2, &c2);
        float2 A[4], Bm[4], Cm[4], T[4], V[4];
        mat_ry(c0, s0, A); mat_rx(c1, s1, Bm); mat_ry(c2, s2, Cm);
        mmul(Bm, A, T); mmul(Cm, T, V);
        if (q == 0) {
            // position 11: h^v_11[beta] = a_0[v] * V_0[beta, v], a_0 = u_11
#pragma unroll
            for (int v = 0; v < 2; ++v) {
                h[v][11][0] = cmul(u[11][v], V[0 * 2 + v]);
                h[v][11][1] = cmul(u[11][v], V[1 * 2 + v]);
            }
        } else {
            const int t = 11 - q;   // a_{t+1} = u_{q-1}
#pragma unroll
            for (int v = 0; v < 2; ++v) {
                float2 g0 = (v == 0) ? u[q - 1][0] : cmuli(u[q - 1][0]);  // i^[0!=v]
                float2 g1 = (v == 1) ? u[q - 1][1] : cmuli(u[q - 1][1]);  // i^[1!=v]
                h[v][t][0] = cadd(cmul(V[0], g0), cmul(V[1], g1));
                h[v][t][1] = cadd(cmul(V[2], g0), cmul(V[3], g1));
            }
        }
    }

    // ---- partial products of inner products (skip m=10 for E0, m=9 for E1) ----
    float2 P0[2][2], P1[2][2];
#pragma unroll
    for (int v = 0; v < 2; ++v)
#pragma unroll
        for (int vp = 0; vp < 2; ++vp) {
            P0[v][vp] = make_float2(1.f, 0.f);
            P1[v][vp] = make_float2(1.f, 0.f);
        }
#pragma unroll
    for (int m = 0; m < 11; ++m) {
#pragma unroll
        for (int v = 0; v < 2; ++v) {
#pragma unroll
            for (int vp = 0; vp < 2; ++vp) {
                float2 S = cadd(cdot(h[v][m][0], h[vp][m][0]),
                                cdot(h[v][m][1], h[vp][m][1]));
                if (m != 10) P0[v][vp] = cmul(P0[v][vp], S);
                if (m != 9)  P1[v][vp] = cmul(P1[v][vp], S);
            }
        }
    }

    // ---- observable O = (RY(t1) RX(t0))^dag Z (RY(t1) RX(t0)) ----
    float ct0, st0, ct1, st1;
    sincosf(0.5f * th[0], &st0, &ct0);
    sincosf(0.5f * th[1], &st1, &ct1);
    float2 Rx[4], Ry[4], M[4];
    mat_rx(ct0, st0, Rx); mat_ry(ct1, st1, Ry); mmul(Ry, Rx, M);
    const float  o00 = (M[0].x * M[0].x + M[0].y * M[0].y)
                     - (M[2].x * M[2].x + M[2].y * M[2].y);
    const float2 o01 = csub(cmul(conjc(M[0]), M[1]), cmul(conjc(M[2]), M[3]));

    // ---- expectations ----
    float2 E0 = make_float2(0.f, 0.f), E1 = make_float2(0.f, 0.f);
#pragma unroll
    for (int w = 0; w < 2; ++w) {
        // O^w off-diagonal: w=0 -> i*o01 ; w=1 -> -i*o01
        float2 Ow01 = (w == 0) ? cmuli(o01) : make_float2(o01.y, -o01.x);
        float2 Ow10 = conjc(Ow01);
#pragma unroll
        for (int v = 0; v < 2; ++v) {
#pragma unroll
            for (int vp = 0; vp < 2; ++vp) {
                float2 A = cdot(h[v][11][w], h[vp][11][w]);
                // quadratic form at factor slot m (m=10 for wire0, m=9 for wire1)
                float2 T0 = cadd(cadd(
                    cscale(o00, csub(cdot(h[v][10][0], h[vp][10][0]),
                                     cdot(h[v][10][1], h[vp][10][1]))),
                    cmul(Ow01, cdot(h[v][10][0], h[vp][10][1]))),
                    cmul(Ow10, cdot(h[v][10][1], h[vp][10][0])));
                float2 T1 = cadd(cadd(
                    cscale(o00, csub(cdot(h[v][9][0], h[vp][9][0]),
                                     cdot(h[v][9][1], h[vp][9][1]))),
                    cmul(Ow01, cdot(h[v][9][0], h[vp][9][1]))),
                    cmul(Ow10, cdot(h[v][9][1], h[vp][9][0])));
                E0 = cadd(E0, cmul(cmul(A, T0), P0[v][vp]));
                E1 = cadd(E1, cmul(cmul(A, T1), P1[v][vp]));
            }
        }
    }

    out[b * 2 + 0] = E0.x;
    out[b * 2 + 1] = E1.x;
}

extern "C" void kernel_launch(void* const* d_in, const int* in_sizes, int n_in,
                              void* d_out, int out_size, void* d_ws, size_t ws_size,
                              hipStream_t stream) {
    const float* x  = (const float*)d_in[0];
    const float* cw = (const float*)d_in[1];
    const float* cb = (const float*)d_in[2];
    const float* th = (const float*)d_in[3];
    float* out = (float*)d_out;
    int B = in_sizes[0] / 196;   // 4096
    qcnn_closed<<<(B + 63) / 64, 64, 0, stream>>>(x, cw, cb, th, out, B);
}

// Round 3
// 17.268 us; speedup vs baseline: 10.5255x; 1.1104x over previous
//
#include <hip/hip_runtime.h>

#define NQ 12
#define THREADS 64

// ---------- complex helpers (float2 = {re, im}) ----------
__device__ __forceinline__ float2 cmul(float2 a, float2 b) {
    return make_float2(a.x * b.x - a.y * b.y, a.x * b.y + a.y * b.x);
}
__device__ __forceinline__ float2 cadd(float2 a, float2 b) { return make_float2(a.x + b.x, a.y + b.y); }
__device__ __forceinline__ float2 csub(float2 a, float2 b) { return make_float2(a.x - b.x, a.y - b.y); }
__device__ __forceinline__ float2 conjc(float2 a) { return make_float2(a.x, -a.y); }
__device__ __forceinline__ float2 cmuli(float2 a) { return make_float2(-a.y, a.x); }  // i*a
__device__ __forceinline__ float2 cdot(float2 a, float2 b) {                          // conj(a)*b
    return make_float2(a.x * b.x + a.y * b.y, a.x * b.y - a.y * b.x);
}
__device__ __forceinline__ float2 cscale(float s, float2 a) { return make_float2(s * a.x, s * a.y); }

__device__ __forceinline__ void mat_rx(float c, float s, float2 m[4]) {
    m[0] = make_float2(c, 0.f);  m[1] = make_float2(0.f, -s);
    m[2] = make_float2(0.f, -s); m[3] = make_float2(c, 0.f);
}
__device__ __forceinline__ void mat_ry(float c, float s, float2 m[4]) {
    m[0] = make_float2(c, 0.f);  m[1] = make_float2(-s, 0.f);
    m[2] = make_float2(s, 0.f);  m[3] = make_float2(c, 0.f);
}
__device__ __forceinline__ void mmul(const float2 A[4], const float2 B[4], float2 C[4]) {
    C[0] = cadd(cmul(A[0], B[0]), cmul(A[1], B[2]));
    C[1] = cadd(cmul(A[0], B[1]), cmul(A[1], B[3]));
    C[2] = cadd(cmul(A[2], B[0]), cmul(A[3], B[2]));
    C[3] = cadd(cmul(A[2], B[1]), cmul(A[3], B[3]));
}

// Same closed-form math as round 2 (rank-2 branch decomposition through each
// iSWAP chain; phases of chain 2 cancel except a diag(i) twist on the
// observable). Restructured: coalesced LDS input staging + single rolling
// loop over q with native trig; only h at positions 9,10 plus (V0, u11) kept.
__global__ __launch_bounds__(THREADS) void qcnn_closed(
    const float* __restrict__ x,      // [B,1,14,14]
    const float* __restrict__ cw,     // [1,1,4,4]
    const float* __restrict__ cb,     // [1]
    const float* __restrict__ th,     // [3]
    float* __restrict__ out,          // [B,2]
    int B)
{
    __shared__ float xs[THREADS][197];   // 197: lane bank-stride 5, conflict-free

    const int tid = threadIdx.x;
    const int b0  = blockIdx.x * THREADS;
    const int b   = b0 + tid;

    // ---- coalesced staging: 64*196 floats = 3136 float4 (49 iters) ----
    {
        const float4* xv = (const float4*)(x + (size_t)b0 * 196);
#pragma unroll
        for (int k = 0; k < 49; ++k) {
            int i4 = tid + k * THREADS;          // < 3136
            float4 v = xv[i4];
            int i  = i4 * 4;
            int row = i / 196, col = i % 196;    // 196%4==0: stays in one row
            xs[row][col + 0] = v.x;
            xs[row][col + 1] = v.y;
            xs[row][col + 2] = v.z;
            xs[row][col + 3] = v.w;
        }
    }
    __syncthreads();

    // ---- conv weights ----
    float wgt[16];
#pragma unroll
    for (int k = 0; k < 16; ++k) wgt[k] = cw[k];
    const float bias = cb[0];
    const float* row = xs[tid];

    // ---- rolling state ----
    float2 u_prev[2];                 // u[q-1]
    float2 V0[4];                     // encoder2 matrix of qubit 0
    float2 h9[2][2], h10[2][2];       // retained branch factors (positions 9,10)
    float2 P0[2][2], P1[2][2];        // products of <h^v_m, h^vp_m>, skip m=10 / m=9
#pragma unroll
    for (int v = 0; v < 2; ++v)
#pragma unroll
        for (int vp = 0; vp < 2; ++vp) {
            P0[v][vp] = make_float2(1.f, 0.f);
            P1[v][vp] = make_float2(1.f, 0.f);
        }

#pragma unroll
    for (int q = 0; q < NQ; ++q) {
        // 3 conv outputs for this qubit: flat o = 3q+i
        float ang[3];
#pragma unroll
        for (int i = 0; i < 3; ++i) {
            int o  = 3 * q + i;
            int oy = o / 6, ox = o % 6;
            float acc = bias;
#pragma unroll
            for (int ky = 0; ky < 4; ++ky)
#pragma unroll
                for (int kx = 0; kx < 4; ++kx)
                    acc += row[(2 * oy + ky) * 14 + (2 * ox + kx)] * wgt[ky * 4 + kx];
            ang[i] = acc;
        }
        float c0 = __cosf(0.5f * ang[0]), s0 = __sinf(0.5f * ang[0]);
        float c1 = __cosf(0.5f * ang[1]), s1 = __sinf(0.5f * ang[1]);
        float c2 = __cosf(0.5f * ang[2]), s2 = __sinf(0.5f * ang[2]);

        // u_cur = RX(a2) RY(a1) RX(a0) |0>   (RY real -> cheap middle step)
        float2 u_cur[2];
        {
            float2 b0c = make_float2(c0, 0.f);          // RX(a0)|0> components
            float2 b1c = make_float2(0.f, -s0);
            float2 t0 = csub(cscale(c1, b0c), cscale(s1, b1c));
            float2 t1 = cadd(cscale(s1, b0c), cscale(c1, b1c));
            u_cur[0] = cadd(cscale(c2, t0), cmul(make_float2(0.f, -s2), t1));
            u_cur[1] = cadd(cmul(make_float2(0.f, -s2), t0), cscale(c2, t1));
        }
        // V = RY(a2) RX(a1) RY(a0)
        float2 V[4];
        {
            float2 A[4], Bm[4], Cm[4], T[4];
            mat_ry(c0, s0, A); mat_rx(c1, s1, Bm); mat_ry(c2, s2, Cm);
            mmul(Bm, A, T); mmul(Cm, T, V);
        }

        if (q == 0) {
#pragma unroll
            for (int k = 0; k < 4; ++k) V0[k] = V[k];
        } else {
            const int t = 11 - q;                 // position of this factor
            float2 hc[2][2];
#pragma unroll
            for (int v = 0; v < 2; ++v) {
                float2 g0 = (v == 0) ? u_prev[0] : cmuli(u_prev[0]);
                float2 g1 = (v == 1) ? u_prev[1] : cmuli(u_prev[1]);
                hc[v][0] = cadd(cmul(V[0], g0), cmul(V[1], g1));
                hc[v][1] = cadd(cmul(V[2], g0), cmul(V[3], g1));
            }
            if (t == 10) {
#pragma unroll
                for (int v = 0; v < 2; ++v) { h10[v][0] = hc[v][0]; h10[v][1] = hc[v][1]; }
            }
            if (t == 9) {
#pragma unroll
                for (int v = 0; v < 2; ++v) { h9[v][0] = hc[v][0]; h9[v][1] = hc[v][1]; }
            }
#pragma unroll
            for (int v = 0; v < 2; ++v)
#pragma unroll
                for (int vp = 0; vp < 2; ++vp) {
                    float2 S = cadd(cdot(hc[v][0], hc[vp][0]),
                                    cdot(hc[v][1], hc[vp][1]));
                    if (t != 10) P0[v][vp] = cmul(P0[v][vp], S);
                    if (t != 9)  P1[v][vp] = cmul(P1[v][vp], S);
                }
        }
        u_prev[0] = u_cur[0];
        u_prev[1] = u_cur[1];
    }

    // h11[v][beta] = u11[v] * V0[beta, v]
    float2 h11[2][2];
#pragma unroll
    for (int v = 0; v < 2; ++v) {
        h11[v][0] = cmul(u_prev[v], V0[0 * 2 + v]);
        h11[v][1] = cmul(u_prev[v], V0[1 * 2 + v]);
    }

    // ---- observable O = (RY(t1) RX(t0))^dag Z (RY(t1) RX(t0)) ----
    float ct0 = __cosf(0.5f * th[0]), st0 = __sinf(0.5f * th[0]);
    float ct1 = __cosf(0.5f * th[1]), st1 = __sinf(0.5f * th[1]);
    float2 Rx[4], Ry[4], M[4];
    mat_rx(ct0, st0, Rx); mat_ry(ct1, st1, Ry); mmul(Ry, Rx, M);
    const float  o00 = (M[0].x * M[0].x + M[0].y * M[0].y)
                     - (M[2].x * M[2].x + M[2].y * M[2].y);
    const float2 o01 = csub(cmul(conjc(M[0]), M[1]), cmul(conjc(M[2]), M[3]));

    // ---- expectations ----
    float2 E0 = make_float2(0.f, 0.f), E1 = make_float2(0.f, 0.f);
#pragma unroll
    for (int w = 0; w < 2; ++w) {
        float2 Ow01 = (w == 0) ? cmuli(o01) : make_float2(o01.y, -o01.x);
        float2 Ow10 = conjc(Ow01);
#pragma unroll
        for (int v = 0; v < 2; ++v) {
#pragma unroll
            for (int vp = 0; vp < 2; ++vp) {
                float2 A = cdot(h11[v][w], h11[vp][w]);
                float2 T0 = cadd(cadd(
                    cscale(o00, csub(cdot(h10[v][0], h10[vp][0]),
                                     cdot(h10[v][1], h10[vp][1]))),
                    cmul(Ow01, cdot(h10[v][0], h10[vp][1]))),
                    cmul(Ow10, cdot(h10[v][1], h10[vp][0])));
                float2 T1 = cadd(cadd(
                    cscale(o00, csub(cdot(h9[v][0], h9[vp][0]),
                                     cdot(h9[v][1], h9[vp][1]))),
                    cmul(Ow01, cdot(h9[v][0], h9[vp][1]))),
                    cmul(Ow10, cdot(h9[v][1], h9[vp][0])));
                E0 = cadd(E0, cmul(cmul(A, T0), P0[v][vp]));
                E1 = cadd(E1, cmul(cmul(A, T1), P1[v][vp]));
            }
        }
    }

    if (b < B) {
        float2 o = make_float2(E0.x, E1.x);
        *((float2*)out + b) = o;
    }
}

extern "C" void kernel_launch(void* const* d_in, const int* in_sizes, int n_in,
                              void* d_out, int out_size, void* d_ws, size_t ws_size,
                              hipStream_t stream) {
    const float* x  = (const float*)d_in[0];
    const float* cw = (const float*)d_in[1];
    const float* cb = (const float*)d_in[2];
    const float* th = (const float*)d_in[3];
    float* out = (float*)d_out;
    int B = in_sizes[0] / 196;   // 4096 (divisible by 64)
    qcnn_closed<<<B / THREADS, THREADS, 0, stream>>>(x, cw, cb, th, out, B);
}

// Round 4
// 12.187 us; speedup vs baseline: 14.9131x; 1.4169x over previous
//
#include <hip/hip_runtime.h>

#define THREADS 64
#define EPB 16      // batch elements per block (4 lanes per element)

// ---------- complex helpers (float2 = {re, im}) ----------
__device__ __forceinline__ float2 cmul(float2 a, float2 b) {
    return make_float2(a.x * b.x - a.y * b.y, a.x * b.y + a.y * b.x);
}
__device__ __forceinline__ float2 cadd(float2 a, float2 b) { return make_float2(a.x + b.x, a.y + b.y); }
__device__ __forceinline__ float2 csub(float2 a, float2 b) { return make_float2(a.x - b.x, a.y - b.y); }
__device__ __forceinline__ float2 conjc(float2 a) { return make_float2(a.x, -a.y); }
__device__ __forceinline__ float2 cmuli(float2 a) { return make_float2(-a.y, a.x); }  // i*a
__device__ __forceinline__ float2 cdot(float2 a, float2 b) {                          // conj(a)*b
    return make_float2(a.x * b.x + a.y * b.y, a.x * b.y - a.y * b.x);
}
__device__ __forceinline__ float2 cscale(float s, float2 a) { return make_float2(s * a.x, s * a.y); }

__device__ __forceinline__ void mat_rx(float c, float s, float2 m[4]) {
    m[0] = make_float2(c, 0.f);  m[1] = make_float2(0.f, -s);
    m[2] = make_float2(0.f, -s); m[3] = make_float2(c, 0.f);
}
__device__ __forceinline__ void mat_ry(float c, float s, float2 m[4]) {
    m[0] = make_float2(c, 0.f);  m[1] = make_float2(-s, 0.f);
    m[2] = make_float2(s, 0.f);  m[3] = make_float2(c, 0.f);
}
__device__ __forceinline__ void mmul(const float2 A[4], const float2 B[4], float2 C[4]) {
    C[0] = cadd(cmul(A[0], B[0]), cmul(A[1], B[2]));
    C[1] = cadd(cmul(A[0], B[1]), cmul(A[1], B[3]));
    C[2] = cadd(cmul(A[2], B[0]), cmul(A[3], B[2]));
    C[3] = cadd(cmul(A[2], B[1]), cmul(A[3], B[3]));
}

__device__ __forceinline__ float2 shfl2(float2 a, int src) {
    return make_float2(__shfl(a.x, src), __shfl(a.y, src));
}
__device__ __forceinline__ float2 shflx2(float2 a, int mask) {
    return make_float2(__shfl_xor(a.x, mask), __shfl_xor(a.y, mask));
}

// Closed-form evaluation (math identical to rounds 2/3), 4 lanes per batch
// element: lane sub owns qubits q = 3*sub .. 3*sub+2.
//   u_q = (RX RY RX)|0>, V_q = RY RX RY  depend only on qubit q's angles.
//   Factor at position t = 11-q (q>=1): h^v_t = V_q * (u_{q-1} twisted by i^[b!=v]).
//   S_t[v][vp] = <h^v_t, h^vp_t>;  P0 = prod_{t != 10} S_t,  P1 = prod_{t != 9}.
//   t=10,9 (q=1,2) and V_0 (q=0) live on lane sub=0; u_11 on lane sub=3.
//   Lane 0 gathers u_11, forms h11[v][b] = u11[v] V0[b][v], evaluates
//   <O_w> with O = (RY RX)^dag Z (RY RX) twisted by diag(i) per w, writes out.
__global__ __launch_bounds__(THREADS) void qcnn_closed4(
    const float* __restrict__ x,      // [B,1,14,14]
    const float* __restrict__ cw,     // [1,1,4,4]
    const float* __restrict__ cb,     // [1]
    const float* __restrict__ th,     // [3]
    float* __restrict__ out,          // [B,2]
    int B)
{
    __shared__ float xs[EPB][197];

    const int tid = threadIdx.x;
    const int sub = tid & 3;          // which qubit-triplet of the element
    const int grp = tid >> 2;         // element within block
    const int b   = blockIdx.x * EPB + grp;

    // ---- coalesced staging: 16*196 floats = 784 float4 ----
    {
        const float4* xv = (const float4*)(x + (size_t)blockIdx.x * EPB * 196);
#pragma unroll
        for (int k = 0; k < 13; ++k) {
            int i4 = tid + k * THREADS;
            if (i4 < (EPB * 196) / 4) {
                float4 v = xv[i4];
                int r  = i4 / 49;              // 49 float4 per row
                int c  = (i4 - r * 49) * 4;
                xs[r][c + 0] = v.x;
                xs[r][c + 1] = v.y;
                xs[r][c + 2] = v.z;
                xs[r][c + 3] = v.w;
            }
        }
    }
    __syncthreads();

    // ---- conv weights (uniform -> scalar regs) ----
    float wgt[16];
#pragma unroll
    for (int k = 0; k < 16; ++k) wgt[k] = cw[k];
    const float bias = cb[0];
    const float* row = xs[grp];

    // ---- 9 conv outputs for this lane: flat o = sub*9 + m ----
    float ang[9];
#pragma unroll
    for (int m = 0; m < 9; ++m) {
        int o  = sub * 9 + m;
        int oy = o / 6, ox = o % 6;
        float acc = bias;
#pragma unroll
        for (int ky = 0; ky < 4; ++ky)
#pragma unroll
            for (int kx = 0; kx < 4; ++kx)
                acc += row[(2 * oy + ky) * 14 + (2 * ox + kx)] * wgt[ky * 4 + kx];
        ang[m] = acc;
    }

    // ---- per-owned-qubit u and V ----
    float2 u[3][2];
    float2 V[3][4];
#pragma unroll
    for (int j = 0; j < 3; ++j) {
        float c0 = __cosf(0.5f * ang[3 * j + 0]), s0 = __sinf(0.5f * ang[3 * j + 0]);
        float c1 = __cosf(0.5f * ang[3 * j + 1]), s1 = __sinf(0.5f * ang[3 * j + 1]);
        float c2 = __cosf(0.5f * ang[3 * j + 2]), s2 = __sinf(0.5f * ang[3 * j + 2]);
        // u = RX(a2) RY(a1) RX(a0) |0>
        {
            float2 b0c = make_float2(c0, 0.f);
            float2 b1c = make_float2(0.f, -s0);
            float2 t0 = csub(cscale(c1, b0c), cscale(s1, b1c));
            float2 t1 = cadd(cscale(s1, b0c), cscale(c1, b1c));
            u[j][0] = cadd(cscale(c2, t0), cmul(make_float2(0.f, -s2), t1));
            u[j][1] = cadd(cmul(make_float2(0.f, -s2), t0), cscale(c2, t1));
        }
        // V = RY(a2) RX(a1) RY(a0)
        {
            float2 A[4], Bm[4], Cm[4], T[4];
            mat_ry(c0, s0, A); mat_rx(c1, s1, Bm); mat_ry(c2, s2, Cm);
            mmul(Bm, A, T); mmul(Cm, T, V[j]);
        }
    }

    // ---- u of previous lane's last qubit (u_{3*sub-1}) ----
    const int srcPrev = tid - (sub ? 1 : 0);     // sub==0: self (unused)
    float2 up0 = shfl2(u[2][0], srcPrev);
    float2 up1 = shfl2(u[2][1], srcPrev);

    // ---- factors, retained h's, partial products ----
    float2 P0p[2][2], P1p[2][2];
#pragma unroll
    for (int v = 0; v < 2; ++v)
#pragma unroll
        for (int vp = 0; vp < 2; ++vp) {
            P0p[v][vp] = make_float2(1.f, 0.f);
            P1p[v][vp] = make_float2(1.f, 0.f);
        }
    float2 V0[4], h9[2][2], h10[2][2];

#pragma unroll
    for (int j = 0; j < 3; ++j) {
        float2 pv0 = (j == 0) ? up0 : u[j - 1][0];
        float2 pv1 = (j == 0) ? up1 : u[j - 1][1];
        float2 hc[2][2];
#pragma unroll
        for (int v = 0; v < 2; ++v) {
            float2 g0 = (v == 0) ? pv0 : cmuli(pv0);
            float2 g1 = (v == 1) ? pv1 : cmuli(pv1);
            hc[v][0] = cadd(cmul(V[j][0], g0), cmul(V[j][1], g1));
            hc[v][1] = cadd(cmul(V[j][2], g0), cmul(V[j][3], g1));
        }
        float2 S[2][2];
#pragma unroll
        for (int v = 0; v < 2; ++v)
#pragma unroll
            for (int vp = 0; vp < 2; ++vp)
                S[v][vp] = cadd(cdot(hc[v][0], hc[vp][0]),
                                cdot(hc[v][1], hc[vp][1]));

        if (sub == 0) {
            if (j == 0) {
#pragma unroll
                for (int k = 0; k < 4; ++k) V0[k] = V[0][k];
            } else if (j == 1) {            // q=1 -> t=10: in P1 only
#pragma unroll
                for (int v = 0; v < 2; ++v) {
                    h10[v][0] = hc[v][0]; h10[v][1] = hc[v][1];
#pragma unroll
                    for (int vp = 0; vp < 2; ++vp)
                        P1p[v][vp] = cmul(P1p[v][vp], S[v][vp]);
                }
            } else {                        // q=2 -> t=9: in P0 only
#pragma unroll
                for (int v = 0; v < 2; ++v) {
                    h9[v][0] = hc[v][0]; h9[v][1] = hc[v][1];
#pragma unroll
                    for (int vp = 0; vp < 2; ++vp)
                        P0p[v][vp] = cmul(P0p[v][vp], S[v][vp]);
                }
            }
        } else {
#pragma unroll
            for (int v = 0; v < 2; ++v)
#pragma unroll
                for (int vp = 0; vp < 2; ++vp) {
                    P0p[v][vp] = cmul(P0p[v][vp], S[v][vp]);
                    P1p[v][vp] = cmul(P1p[v][vp], S[v][vp]);
                }
        }
    }

    // ---- combine partial products across the 4 lanes of the group ----
#pragma unroll
    for (int d = 1; d <= 2; d <<= 1) {
#pragma unroll
        for (int v = 0; v < 2; ++v)
#pragma unroll
            for (int vp = 0; vp < 2; ++vp) {
                P0p[v][vp] = cmul(P0p[v][vp], shflx2(P0p[v][vp], d));
                P1p[v][vp] = cmul(P1p[v][vp], shflx2(P1p[v][vp], d));
            }
    }

    // ---- u_11 (lane sub=3's last u) to everyone in the group ----
    const int srcLast = tid | 3;
    float2 u11_0 = shfl2(u[2][0], srcLast);
    float2 u11_1 = shfl2(u[2][1], srcLast);

    if (sub == 0) {
        float2 h11[2][2];
        h11[0][0] = cmul(u11_0, V0[0]); h11[0][1] = cmul(u11_0, V0[2]);
        h11[1][0] = cmul(u11_1, V0[1]); h11[1][1] = cmul(u11_1, V0[3]);

        // observable O = (RY(t1) RX(t0))^dag Z (RY(t1) RX(t0))
        float ct0 = __cosf(0.5f * th[0]), st0 = __sinf(0.5f * th[0]);
        float ct1 = __cosf(0.5f * th[1]), st1 = __sinf(0.5f * th[1]);
        float2 Rx[4], Ry[4], M[4];
        mat_rx(ct0, st0, Rx); mat_ry(ct1, st1, Ry); mmul(Ry, Rx, M);
        const float  o00 = (M[0].x * M[0].x + M[0].y * M[0].y)
                         - (M[2].x * M[2].x + M[2].y * M[2].y);
        const float2 o01 = csub(cmul(conjc(M[0]), M[1]), cmul(conjc(M[2]), M[3]));

        float2 E0 = make_float2(0.f, 0.f), E1 = make_float2(0.f, 0.f);
#pragma unroll
        for (int w = 0; w < 2; ++w) {
            float2 Ow01 = (w == 0) ? cmuli(o01) : make_float2(o01.y, -o01.x);
            float2 Ow10 = conjc(Ow01);
#pragma unroll
            for (int v = 0; v < 2; ++v) {
#pragma unroll
                for (int vp = 0; vp < 2; ++vp) {
                    float2 A = cdot(h11[v][w], h11[vp][w]);
                    float2 T0 = cadd(cadd(
                        cscale(o00, csub(cdot(h10[v][0], h10[vp][0]),
                                         cdot(h10[v][1], h10[vp][1]))),
                        cmul(Ow01, cdot(h10[v][0], h10[vp][1]))),
                        cmul(Ow10, cdot(h10[v][1], h10[vp][0])));
                    float2 T1 = cadd(cadd(
                        cscale(o00, csub(cdot(h9[v][0], h9[vp][0]),
                                         cdot(h9[v][1], h9[vp][1]))),
                        cmul(Ow01, cdot(h9[v][0], h9[vp][1]))),
                        cmul(Ow10, cdot(h9[v][1], h9[vp][0])));
                    E0 = cadd(E0, cmul(cmul(A, T0), P0p[v][vp]));
                    E1 = cadd(E1, cmul(cmul(A, T1), P1p[v][vp]));
                }
            }
        }
        if (b < B)
            ((float2*)out)[b] = make_float2(E0.x, E1.x);
    }
}

extern "C" void kernel_launch(void* const* d_in, const int* in_sizes, int n_in,
                              void* d_out, int out_size, void* d_ws, size_t ws_size,
                              hipStream_t stream) {
    const float* x  = (const float*)d_in[0];
    const float* cw = (const float*)d_in[1];
    const float* cb = (const float*)d_in[2];
    const float* th = (const float*)d_in[3];
    float* out = (float*)d_out;
    int B = in_sizes[0] / 196;                 // 4096, divisible by EPB
    qcnn_closed4<<<B / EPB, THREADS, 0, stream>>>(x, cw, cb, th, out, B);
}